// Round 5
// baseline (53.830 us; speedup 1.0000x reference)
//
#include <hip/hip_runtime.h>
#include <hip/hip_bf16.h>

// BatchedNeRFMLP: B=64, N=16384, HID=128, POS_IN=63 (+bias col -> K=64), DIR_IN=27
// params per batch (TOTAL=8789 fp32):
//   pw [128][63] @0   pb[128]@8064   sw[128]@8192  sb@8320
//   cw [3][155] @8321 cb[3]@8786
// out: sigma (B*N) then rgb (B*N*3), fp32.
//
// Layer-1: mfma_f32_32x32x16_bf16, D[h][ray] (A=weights reg-stationary, B=ENC^T
// via XOR-swizzled LDS). ENC K-order: [x0,x1,x2,1.0, f0:(s0,s1,s2,c0,c1,c2),...f9]
// bias=pb rides k=3 (enc k=3 is constant 1.0).
// Head (sigma,r,g,b; K=128): W2 K-order permuted so each lane's naturally-held
// D-rows are its B-frag k-slots -> repack is relu+pack of own regs, no shuffles.
//
// Pipeline (per wave, rows are wave-private):
//   iter body: ds_read x8 (enc it) -> encode(it+1) VALU + ds_write x8 (same rows)
//              -> MFMA(it) -> tail(it).
// Per-wave DS ops execute in order: reads precede writes in program order, so
// no WAR through LDS; compiler emits counted lgkmcnt (writes stay in flight).
// No __syncthreads / no manual lgkmcnt(0) drains anywhere.

#define NB 64
#define NRAY 16384
#define NTOTAL 8789
#define PI_F 3.14159265358979323846f

typedef short bf16x8 __attribute__((ext_vector_type(8)));
typedef float f32x16 __attribute__((ext_vector_type(16)));

union U8 { unsigned u[4]; bf16x8 v; };

__device__ __forceinline__ unsigned pk2(float a, float b) {
    float2 t; t.x = a; t.y = b;
    __hip_bfloat162 h = __float22bfloat162_rn(t);   // v_cvt_pk_bf16_f32
    return *reinterpret_cast<unsigned*>(&h);
}

__global__ __launch_bounds__(256, 2) void nerf_mfma_kernel(
    const float* __restrict__ pos,
    const float* __restrict__ dir,
    const float* __restrict__ params,
    float* __restrict__ out)
{
    const int tid  = threadIdx.x;
    const int lane = tid & 63;
    const int wid  = tid >> 6;
    const int hi   = lane >> 5;
    const int l31  = lane & 31;

    const int b     = blockIdx.x >> 4;          // 16 blocks per batch
    const int chunk = (blockIdx.x & 15) << 10;  // 1024 rays per block
    const float* __restrict__ p = params + b * NTOTAL;

    __shared__ uint4 encs[2048];                // 256 rows x 128B, swizzled
    char* encb = reinterpret_cast<char*>(encs);

    // ---------------- register-stationary A-frags --------------------------
    // layer-1: k<3 -> d=k ; k==3 -> pb[h] ; k>=4 -> d=k-1
    bf16x8 aw[4][4];
    #pragma unroll
    for (int mt = 0; mt < 4; ++mt) {
        const int hrow = mt * 32 + l31;
        const float* wrow = p + hrow * 63;
        const float bias = p[8064 + hrow];
        #pragma unroll
        for (int ks = 0; ks < 4; ++ks) {
            U8 u;
            #pragma unroll
            for (int j = 0; j < 4; ++j) {
                const int k0 = ks * 16 + hi * 8 + 2 * j;
                const int k1 = k0 + 1;
                const float e0 = (k0 < 3) ? wrow[k0] : (k0 == 3 ? bias : wrow[k0 - 1]);
                const float e1 = (k1 < 3) ? wrow[k1] : (k1 == 3 ? bias : wrow[k1 - 1]);
                u.u[j] = pk2(e0, e1);
            }
            aw[mt][ks] = u.v;
        }
    }
    // head weights, K permuted: slot(s,hi,i) -> h = 32*(s>>1)+16*(s&1)+4hi+(i&3)+8*(i>>2)
    bf16x8 haw[8];
    {
        const int r = l31 & 3;  // 0=sigma(sw), 1..3 = cw rows
        const float* w2 = (r == 0) ? (p + 8192) : (p + 8321 + (r - 1) * 155);
        #pragma unroll
        for (int s = 0; s < 8; ++s) {
            const int base = 32 * (s >> 1) + 16 * (s & 1) + 4 * hi;
            U8 u;
            #pragma unroll
            for (int j = 0; j < 4; ++j) {
                const int i0 = 2 * j, i1 = 2 * j + 1;
                u.u[j] = pk2(w2[base + (i0 & 3) + 8 * (i0 >> 2)],
                             w2[base + (i1 & 3) + 8 * (i1 >> 2)]);
            }
            haw[s] = u.v;
        }
    }

    f32x16 FZ;
    #pragma unroll
    for (int i = 0; i < 16; ++i) FZ[i] = 0.f;

    const float sb  = p[8320];
    const float cb0 = p[8786], cb1 = p[8787], cb2 = p[8788];
    const float* __restrict__ cwr  = p + 8321 + 128;
    const float* __restrict__ cwg  = p + 8321 + 155 + 128;
    const float* __restrict__ cwb2 = p + 8321 + 310 + 128;

    const int rayBlock = b * NRAY + chunk;
    float* __restrict__ rgbout = out + (long)NB * NRAY;
    const long pb0 = (long)(rayBlock + tid) * 3;

    // encode row `tid` of LDS with this thread's position Pv
    auto encode_row = [&](const float3 Pv) {
        const int swz = (tid & 7) << 4;
        char* myrow = encb + tid * 128;
        float s0, c0, s1, c1, s2, c2;
        __sincosf(Pv.x * PI_F, &s0, &c0);
        __sincosf(Pv.y * PI_F, &s1, &c1);
        __sincosf(Pv.z * PI_F, &s2, &c2);
        unsigned w[32];
        w[0] = pk2(Pv.x, Pv.y);
        w[1] = pk2(Pv.z, 1.0f);
        #pragma unroll
        for (int f = 0; f < 10; ++f) {
            w[2 + 3 * f] = pk2(s0, s1);
            w[3 + 3 * f] = pk2(s2, c0);
            w[4 + 3 * f] = pk2(c1, c2);
            if (f < 9) {
                float t;
                t = 2.f * s0 * c0; c0 = fmaf(-2.f * s0, s0, 1.f); s0 = t;
                t = 2.f * s1 * c1; c1 = fmaf(-2.f * s1, s1, 1.f); s1 = t;
                t = 2.f * s2 * c2; c2 = fmaf(-2.f * s2, s2, 1.f); s2 = t;
            }
        }
        #pragma unroll
        for (int cq = 0; cq < 8; ++cq) {
            uint4 v;
            v.x = w[4 * cq + 0]; v.y = w[4 * cq + 1];
            v.z = w[4 * cq + 2]; v.w = w[4 * cq + 3];
            *reinterpret_cast<uint4*>(myrow + ((cq * 16) ^ swz)) = v;
        }
    };

    // prologue: encode iter-0, prefetch iter-1 pos and iter-0 dir
    float3 P0 = *reinterpret_cast<const float3*>(pos + pb0);
    float3 Pn = *reinterpret_cast<const float3*>(pos + pb0 + 768);
    float3 Dc = *reinterpret_cast<const float3*>(dir + pb0);
    encode_row(P0);

    #pragma unroll 1
    for (int it = 0; it < 4; ++it) {
        const int ray = rayBlock + it * 256 + tid;

        float3 Pn2, Dn;
        if (it < 2) Pn2 = *reinterpret_cast<const float3*>(pos + pb0 + (it + 2) * 768);
        if (it < 3) Dn  = *reinterpret_cast<const float3*>(dir + pb0 + (it + 1) * 768);

        // ---- all 8 B-frag reads first (rows hold enc(it)) ------------------
        bf16x8 be[2][4];
        #pragma unroll
        for (int nt = 0; nt < 2; ++nt) {
            const int row = wid * 64 + nt * 32 + l31;
            const int swz = (row & 7) << 4;
            #pragma unroll
            for (int ks = 0; ks < 4; ++ks)
                be[nt][ks] = *reinterpret_cast<const bf16x8*>(
                    encb + row * 128 + ((ks * 32 + hi * 16) ^ swz));
        }

        // ---- encode(it+1) + writes to same rows (after reads: DS in-order) -
        if (it < 3) encode_row(Pn);

        // ---- layer-1 + head MFMA --------------------------------------------
        __builtin_amdgcn_s_setprio(1);
        float hres[2][4];
        #pragma unroll
        for (int nt = 0; nt < 2; ++nt) {
            f32x16 hacc;
            #pragma unroll
            for (int mt = 0; mt < 4; ++mt) {
                f32x16 accm = __builtin_amdgcn_mfma_f32_32x32x16_bf16(aw[mt][0], be[nt][0], FZ, 0, 0, 0);
                accm = __builtin_amdgcn_mfma_f32_32x32x16_bf16(aw[mt][1], be[nt][1], accm, 0, 0, 0);
                accm = __builtin_amdgcn_mfma_f32_32x32x16_bf16(aw[mt][2], be[nt][2], accm, 0, 0, 0);
                accm = __builtin_amdgcn_mfma_f32_32x32x16_bf16(aw[mt][3], be[nt][3], accm, 0, 0, 0);

                #pragma unroll
                for (int t = 0; t < 2; ++t) {
                    const int rb = t * 8;
                    U8 u;
                    #pragma unroll
                    for (int j = 0; j < 4; ++j)
                        u.u[j] = pk2(fmaxf(accm[rb + 2 * j], 0.f),
                                     fmaxf(accm[rb + 2 * j + 1], 0.f));
                    hacc = __builtin_amdgcn_mfma_f32_32x32x16_bf16(
                        haw[2 * mt + t], u.v, (mt == 0 && t == 0) ? FZ : hacc, 0, 0, 0);
                }
            }
            hres[nt][0] = hacc[0]; hres[nt][1] = hacc[1];
            hres[nt][2] = hacc[2]; hres[nt][3] = hacc[3];
        }
        __builtin_amdgcn_s_setprio(0);

        // ---- per-ray tail: dir-encode folded into head FMAs ----------------
        const float hv0 = hi ? hres[1][0] : hres[0][0];
        const float hv1 = hi ? hres[1][1] : hres[0][1];
        const float hv2 = hi ? hres[1][2] : hres[0][2];
        const float hv3 = hi ? hres[1][3] : hres[0][3];

        float sig = hv0 + sb;
        float cr  = hv1 + cb0;
        float cg  = hv2 + cb1;
        float cbl = hv3 + cb2;

        {
            float s0, c0, s1, c1, s2, c2;
            __sincosf(Dc.x * PI_F, &s0, &c0);
            __sincosf(Dc.y * PI_F, &s1, &c1);
            __sincosf(Dc.z * PI_F, &s2, &c2);
            cr  = fmaf(Dc.x, cwr[0], cr);  cg  = fmaf(Dc.x, cwg[0], cg);  cbl = fmaf(Dc.x, cwb2[0], cbl);
            cr  = fmaf(Dc.y, cwr[1], cr);  cg  = fmaf(Dc.y, cwg[1], cg);  cbl = fmaf(Dc.y, cwb2[1], cbl);
            cr  = fmaf(Dc.z, cwr[2], cr);  cg  = fmaf(Dc.z, cwg[2], cg);  cbl = fmaf(Dc.z, cwb2[2], cbl);
            #pragma unroll
            for (int f = 0; f < 4; ++f) {
                const int j = 3 + 6 * f;
                cr = fmaf(s0, cwr[j+0], cr); cg = fmaf(s0, cwg[j+0], cg); cbl = fmaf(s0, cwb2[j+0], cbl);
                cr = fmaf(s1, cwr[j+1], cr); cg = fmaf(s1, cwg[j+1], cg); cbl = fmaf(s1, cwb2[j+1], cbl);
                cr = fmaf(s2, cwr[j+2], cr); cg = fmaf(s2, cwg[j+2], cg); cbl = fmaf(s2, cwb2[j+2], cbl);
                cr = fmaf(c0, cwr[j+3], cr); cg = fmaf(c0, cwg[j+3], cg); cbl = fmaf(c0, cwb2[j+3], cbl);
                cr = fmaf(c1, cwr[j+4], cr); cg = fmaf(c1, cwg[j+4], cg); cbl = fmaf(c1, cwb2[j+4], cbl);
                cr = fmaf(c2, cwr[j+5], cr); cg = fmaf(c2, cwg[j+5], cg); cbl = fmaf(c2, cwb2[j+5], cbl);
                if (f < 3) {
                    float t;
                    t = 2.f * s0 * c0; c0 = fmaf(-2.f * s0, s0, 1.f); s0 = t;
                    t = 2.f * s1 * c1; c1 = fmaf(-2.f * s1, s1, 1.f); s1 = t;
                    t = 2.f * s2 * c2; c2 = fmaf(-2.f * s2, s2, 1.f); s2 = t;
                }
            }
        }

        cr  = 1.0f / (1.0f + __expf(-cr));
        cg  = 1.0f / (1.0f + __expf(-cg));
        cbl = 1.0f / (1.0f + __expf(-cbl));

        out[ray] = sig;
        float3 rgbv; rgbv.x = cr; rgbv.y = cg; rgbv.z = cbl;
        *reinterpret_cast<float3*>(rgbout + (long)ray * 3) = rgbv;

        Pn = Pn2; Dc = Dn;
    }
}

extern "C" void kernel_launch(void* const* d_in, const int* in_sizes, int n_in,
                              void* d_out, int out_size, void* d_ws, size_t ws_size,
                              hipStream_t stream) {
    const float* pos    = (const float*)d_in[0];
    const float* dirs   = (const float*)d_in[1];
    const float* params = (const float*)d_in[2];
    float* out = (float*)d_out;

    dim3 grid(1024);   // 16 blocks/batch x 64 batches, 1024 rays each
    dim3 block(256);
    nerf_mfma_kernel<<<grid, block, 0, stream>>>(pos, dirs, params, out);
}